// Round 1
// baseline (435.086 us; speedup 1.0000x reference)
//
#include <hip/hip_runtime.h>

#define BB 4
#define CC 3
#define HH 384
#define WW 384
#define HW (HH * WW)
#define KK 5
#define RR 2
#define K2 25

static constexpr float INV_Z2 = 1.0f / (0.15f * 0.15f);

// ---------------------------------------------------------------------------
// prep: per-pixel 5x5 bilateral affinity, normalized; also x0 = feat * mask
// Out-of-bounds taps: reference pads img with 0, and (0 - (img+10)) blows the
// exponent to ~-1e4 -> fp32 exp underflows to exactly 0. So skipping them is
// exact.
// ---------------------------------------------------------------------------
__global__ __launch_bounds__(256) void prep_kernel(
    const float* __restrict__ img, const float* __restrict__ feat,
    const float* __restrict__ mask, float* __restrict__ wgt,
    float* __restrict__ x0)
{
    int idx = blockIdx.x * blockDim.x + threadIdx.x;
    if (idx >= BB * HW) return;
    int b   = idx / HW;
    int rem = idx - b * HW;
    int h   = rem / WW;
    int wc  = rem - h * WW;

    const float* imgb = img + (size_t)b * CC * HW;
    float c0 = imgb[0 * HW + rem] + 10.0f;
    float c1 = imgb[1 * HW + rem] + 10.0f;
    float c2 = imgb[2 * HW + rem] + 10.0f;

    float aff[K2];
    float sumz = 1e-10f;
#pragma unroll
    for (int t = 0; t < K2; ++t) {
        int di = t / KK - RR, dj = t % KK - RR;
        int hh = h + di, ww = wc + dj;
        float a = 0.0f;
        if (hh >= 0 && hh < HH && ww >= 0 && ww < WW) {
            int q = hh * WW + ww;
            float d0 = imgb[0 * HW + q] + 10.0f - c0;
            float d1 = imgb[1 * HW + q] + 10.0f - c1;
            float d2 = imgb[2 * HW + q] + 10.0f - c2;
            a = __expf(-(d0 * d0 + d1 * d1 + d2 * d2) * INV_Z2);
        }
        aff[t] = a;
        sumz += a;
    }
    float inv = 1.0f / sumz;
#pragma unroll
    for (int t = 0; t < K2; ++t)
        wgt[((size_t)b * K2 + t) * HW + rem] = aff[t] * inv;

    x0[idx] = feat[idx] * mask[idx];
}

// ---------------------------------------------------------------------------
// One propagation iteration: x_out(p) = mask(p) * sum_t w(p,t) * x_in(p + d_t)
// Interior fast path is branch-free (borders are <2.1% of pixels).
// ---------------------------------------------------------------------------
__global__ __launch_bounds__(256) void iter_kernel(
    const float* __restrict__ wgt, const float* __restrict__ xin,
    const float* __restrict__ mask, float* __restrict__ xout)
{
    int idx = blockIdx.x * blockDim.x + threadIdx.x;
    if (idx >= BB * HW) return;
    int b   = idx / HW;
    int rem = idx - b * HW;
    int h   = rem / WW;
    int wc  = rem - h * WW;

    const float* wb = wgt + (size_t)b * K2 * HW + rem;
    const float* xb = xin + (size_t)b * HW;

    float acc = 0.0f;
    if (h >= RR && h < HH - RR && wc >= RR && wc < WW - RR) {
#pragma unroll
        for (int t = 0; t < K2; ++t) {
            int di = t / KK - RR, dj = t % KK - RR;
            acc += wb[(size_t)t * HW] * xb[rem + di * WW + dj];
        }
    } else {
#pragma unroll
        for (int t = 0; t < K2; ++t) {
            int di = t / KK - RR, dj = t % KK - RR;
            int hh = h + di, ww = wc + dj;
            if (hh >= 0 && hh < HH && ww >= 0 && ww < WW)
                acc += wb[(size_t)t * HW] * xb[hh * WW + ww];
        }
    }
    xout[idx] = acc * mask[idx];
}

extern "C" void kernel_launch(void* const* d_in, const int* in_sizes, int n_in,
                              void* d_out, int out_size, void* d_ws, size_t ws_size,
                              hipStream_t stream)
{
    const float* img  = (const float*)d_in[0];
    const float* feat = (const float*)d_in[1];
    const float* mask = (const float*)d_in[2];
    float* out = (float*)d_out;

    float* wgt = (float*)d_ws;                       // B*25*HW fp32  (~59 MB)
    float* xa  = wgt + (size_t)BB * K2 * HW;         // B*HW fp32
    float* xb  = xa + (size_t)BB * HW;               // B*HW fp32

    const int n = BB * HW;
    const int blocks = (n + 255) / 256;

    prep_kernel<<<blocks, 256, 0, stream>>>(img, feat, mask, wgt, xa);

    float* cur = xa;
    float* nxt = xb;
    for (int it = 0; it < 19; ++it) {
        iter_kernel<<<blocks, 256, 0, stream>>>(wgt, cur, mask, nxt);
        float* t = cur; cur = nxt; nxt = t;
    }
    iter_kernel<<<blocks, 256, 0, stream>>>(wgt, cur, mask, out);
}